// Round 2
// baseline (1019.959 us; speedup 1.0000x reference)
//
#include <hip/hip_runtime.h>
#include <hip/hip_bf16.h>

// MoE: N=8192 tokens, D=1024, H=4096, E=8 experts, top-k=2.
// Sparse grouped-GEMM: 256x256x32 tiles, 8 waves, single-buffered LDS.

#define NTOK 8192
#define DDIM 1024
#define HDIM 4096
#define NEXP 8
#define NASSIGN (NTOK * 2)   // 16384 (token, expert) assignments
#define MAX_MT 72            // max ceil-sum of per-expert 256-row tiles

typedef __bf16 bf16_t;
typedef __bf16 bf16x8 __attribute__((ext_vector_type(8)));
typedef float f32x4 __attribute__((ext_vector_type(4)));

// async global->LDS, 16B per lane; LDS dest = wave-uniform base + lane*16
#define GLOAD16(gptr, lptr)                                                    \
  __builtin_amdgcn_global_load_lds(                                            \
      (const __attribute__((address_space(1))) void*)(gptr),                   \
      (__attribute__((address_space(3))) void*)(lptr), 16, 0, 0)

// ---------------- conversion kernels ----------------

__global__ void __launch_bounds__(256) cvt_x_kernel(
    const float* __restrict__ in, bf16_t* __restrict__ out) {
  const int i = (blockIdx.x * 256 + threadIdx.x) * 8;
  const float4 a = *(const float4*)(in + i);
  const float4 b = *(const float4*)(in + i + 4);
  bf16x8 o;
  o[0] = (bf16_t)a.x; o[1] = (bf16_t)a.y; o[2] = (bf16_t)a.z; o[3] = (bf16_t)a.w;
  o[4] = (bf16_t)b.x; o[5] = (bf16_t)b.y; o[6] = (bf16_t)b.z; o[7] = (bf16_t)b.w;
  *(bf16x8*)(out + i) = o;
}

// in: [E][R][C] f32  ->  out: [E][C][R] bf16   (tiled 32x32 transpose)
__global__ void __launch_bounds__(256) transpose_cvt_kernel(
    const float* __restrict__ in, bf16_t* __restrict__ out, int R, int C) {
  __shared__ float tile[32][33];
  const size_t mat = (size_t)R * C;
  const float* ip = in + (size_t)blockIdx.z * mat;
  bf16_t* op = out + (size_t)blockIdx.z * mat;
  const int c0 = blockIdx.x * 32, r0 = blockIdx.y * 32;
  const int tx = threadIdx.x, ty = threadIdx.y;  // (32, 8)
#pragma unroll
  for (int i = 0; i < 4; ++i) {
    const int r = ty + 8 * i;
    tile[r][tx] = ip[(size_t)(r0 + r) * C + (c0 + tx)];
  }
  __syncthreads();
#pragma unroll
  for (int i = 0; i < 4; ++i) {
    const int r = ty + 8 * i;
    op[(size_t)(c0 + r) * R + (r0 + tx)] = (bf16_t)tile[tx][r];
  }
}

// ---------------- router ----------------

__global__ void __launch_bounds__(256) router_kernel(
    const float* __restrict__ x, const float* __restrict__ Wr,
    const float* __restrict__ br, int2* __restrict__ ids,
    float2* __restrict__ prs, int* __restrict__ counts) {
  const int n = blockIdx.x;
  const int t = threadIdx.x;
  const float* xr = x + (size_t)n * DDIM;
  float acc[NEXP];
#pragma unroll
  for (int e = 0; e < NEXP; ++e) acc[e] = 0.f;
#pragma unroll
  for (int j = 0; j < DDIM / 256; ++j) {
    const int d = t + 256 * j;
    const float xv = xr[d];
    const float* w = Wr + (size_t)d * NEXP;
#pragma unroll
    for (int e = 0; e < NEXP; ++e) acc[e] += xv * w[e];
  }
  __shared__ float red[256][NEXP];
#pragma unroll
  for (int e = 0; e < NEXP; ++e) red[t][e] = acc[e];
  __syncthreads();
  for (int s = 128; s >= 1; s >>= 1) {  // fixed tree -> deterministic logits
    if (t < s) {
#pragma unroll
      for (int e = 0; e < NEXP; ++e) red[t][e] += red[t + s][e];
    }
    __syncthreads();
  }
  if (t == 0) {
    float l[NEXP];
#pragma unroll
    for (int e = 0; e < NEXP; ++e) l[e] = red[0][e] + br[e];
    int i1 = 0; float v1 = l[0];
    for (int e = 1; e < NEXP; ++e)
      if (l[e] > v1) { v1 = l[e]; i1 = e; }
    int i2 = (i1 == 0) ? 1 : 0; float v2 = l[i2];
    for (int e = 0; e < NEXP; ++e)
      if (e != i1 && l[e] > v2) { v2 = l[e]; i2 = e; }
    float denom = 0.f;
    for (int e = 0; e < NEXP; ++e) denom += expf(l[e] - v1);
    const float p1 = expf(v1 - v1) / denom;
    const float p2 = expf(v2 - v1) / denom;
    ids[n] = make_int2(i1, i2);
    prs[n] = make_float2(p1, p2);
    atomicAdd(&counts[i1], 1);
    atomicAdd(&counts[i2], 1);
  }
}

// scan (thread 0) + aux loss (all 256 threads), one kernel
__global__ void __launch_bounds__(256) scan_aux_kernel(
    const int* __restrict__ counts, int* __restrict__ offsets,
    int* __restrict__ tmap, const int2* __restrict__ ids,
    const float2* __restrict__ prs, float* __restrict__ aux_out) {
  const int t = threadIdx.x;
  if (t == 0) {
    int off = 0, nt = 0;
    for (int e = 0; e < NEXP; ++e) {
      offsets[e] = off;
      const int c = counts[e];
      for (int m0 = 0; m0 < c; m0 += 256) {
        tmap[nt] = e;
        tmap[MAX_MT + nt] = m0;
        ++nt;
      }
      off += c;
    }
    offsets[NEXP] = off;
    tmap[2 * MAX_MT] = nt;
  }
  // aux loss
  float imp[NEXP];
#pragma unroll
  for (int e = 0; e < NEXP; ++e) imp[e] = 0.f;
  for (int n = t; n < NTOK; n += 256) {
    const int2 id = ids[n];
    const float2 pr = prs[n];
#pragma unroll
    for (int e = 0; e < NEXP; ++e)
      imp[e] += (id.x == e ? pr.x : 0.f) + (id.y == e ? pr.y : 0.f);
  }
  __shared__ float red[256][NEXP];
#pragma unroll
  for (int e = 0; e < NEXP; ++e) red[t][e] = imp[e];
  __syncthreads();
  for (int s = 128; s >= 1; s >>= 1) {
    if (t < s) {
#pragma unroll
      for (int e = 0; e < NEXP; ++e) red[t][e] += red[t + s][e];
    }
    __syncthreads();
  }
  if (t == 0) {
    float m = 0.f;
    for (int e = 0; e < NEXP; ++e) m += red[0][e];
    m *= (1.f / NEXP);
    float v = 0.f;
    for (int e = 0; e < NEXP; ++e) {
      const float d = red[0][e] - m;
      v += d * d;
    }
    v *= (1.f / (NEXP - 1));  // ddof=1
    aux_out[0] = v / (m * m + 1e-9f);
  }
}

__global__ void __launch_bounds__(256) scatter_kernel(
    const int2* __restrict__ ids, const float2* __restrict__ prs,
    const int* __restrict__ offsets, int* __restrict__ cursor,
    int* __restrict__ btok, float* __restrict__ bprob) {
  const int n = blockIdx.x * 256 + threadIdx.x;
  if (n >= NTOK) return;
  const int2 id = ids[n];
  const float2 pr = prs[n];
  int p = atomicAdd(&cursor[id.x], 1);
  btok[offsets[id.x] + p] = n;
  bprob[offsets[id.x] + p] = pr.x;
  p = atomicAdd(&cursor[id.y], 1);
  btok[offsets[id.y] + p] = n;
  bprob[offsets[id.y] + p] = pr.y;
}

// ---------------- grouped GEMMs: 256x256x32, 8 waves, single-buffered ------
// wave grid 2(M) x 4(N); per-wave output 128x64 = acc[8][4] f32x4.

// h[assign, :] = relu(x[btok[assign]] @ W1[e] + b1[e]);  N = HDIM, K = DDIM
__global__ void __launch_bounds__(512, 2) gemm1_kernel(
    const bf16_t* __restrict__ xb, const bf16_t* __restrict__ W1t,
    const float* __restrict__ b1, const int* __restrict__ btok,
    const int* __restrict__ offsets, const int* __restrict__ counts,
    const int* __restrict__ tmap, bf16_t* __restrict__ h) {
  const int tidx = blockIdx.y;
  if (tidx >= tmap[2 * MAX_MT]) return;
  const int e = tmap[tidx];
  const int m0 = tmap[MAX_MT + tidx];
  const int cnt = counts[e];
  const int aoff = offsets[e];
  const int n0 = blockIdx.x * 256;

  __shared__ __align__(16) bf16_t Al[256 * 32];  // 16 KB
  __shared__ __align__(16) bf16_t Bl[256 * 32];  // 16 KB

  const int tid = threadIdx.x;
  const int wave = tid >> 6;
  const int lane = tid & 63;

  // per-thread global source bases for 2 staging chunks each of A and B
  const bf16_t* asrc[2];
  const bf16_t* bsrc[2];
#pragma unroll
  for (int j = 0; j < 2; ++j) {
    const int c = j * 512 + tid;   // 16B-chunk index in [0,1024)
    const int r = c >> 2;          // tile row (4 chunks of 16B per 64B row)
    const int kc = (c & 3) * 8;    // k element offset
    int arow = m0 + r;
    if (arow > cnt - 1) arow = cnt - 1;  // clamp (stores masked later)
    const int tok = btok[aoff + arow];
    asrc[j] = xb + (size_t)tok * DDIM + kc;
    bsrc[j] = W1t + ((size_t)e * HDIM + n0 + r) * DDIM + kc;
  }
  char* AlB = (char*)Al + wave * 1024;
  char* BlB = (char*)Bl + wave * 1024;

  f32x4 acc[8][4];
#pragma unroll
  for (int mf = 0; mf < 8; ++mf)
#pragma unroll
    for (int nf = 0; nf < 4; ++nf) acc[mf][nf] = (f32x4){0.f, 0.f, 0.f, 0.f};

  const int wr = (wave >> 2) * 128;  // wave M origin
  const int wc = (wave & 3) * 64;    // wave N origin
  const int lrow = lane & 15;
  const int lk = (lane >> 4) * 8;

  for (int k0 = 0; k0 < DDIM; k0 += 32) {
    GLOAD16(asrc[0] + k0, AlB);
    GLOAD16(asrc[1] + k0, AlB + 8192);
    GLOAD16(bsrc[0] + k0, BlB);
    GLOAD16(bsrc[1] + k0, BlB + 8192);
    __syncthreads();
    bf16x8 af[8], bfr[4];
#pragma unroll
    for (int mf = 0; mf < 8; ++mf)
      af[mf] = *(const bf16x8*)&Al[(wr + mf * 16 + lrow) * 32 + lk];
#pragma unroll
    for (int nf = 0; nf < 4; ++nf)
      bfr[nf] = *(const bf16x8*)&Bl[(wc + nf * 16 + lrow) * 32 + lk];
#pragma unroll
    for (int mf = 0; mf < 8; ++mf)
#pragma unroll
      for (int nf = 0; nf < 4; ++nf)
        acc[mf][nf] = __builtin_amdgcn_mfma_f32_16x16x32_bf16(
            af[mf], bfr[nf], acc[mf][nf], 0, 0, 0);
    __syncthreads();
  }

  // epilogue: h = relu(acc + b1), bf16
  const int rbase = (lane >> 4) * 4;
  const float* b1e = b1 + (size_t)e * HDIM + n0;
#pragma unroll
  for (int nf = 0; nf < 4; ++nf) {
    const int cl = wc + nf * 16 + lrow;
    const float bb = b1e[cl];
#pragma unroll
    for (int mf = 0; mf < 8; ++mf) {
#pragma unroll
      for (int r = 0; r < 4; ++r) {
        const int grow = wr + mf * 16 + rbase + r;
        if (m0 + grow < cnt)
          h[(size_t)(aoff + m0 + grow) * HDIM + (n0 + cl)] =
              (bf16_t)fmaxf(acc[mf][nf][r] + bb, 0.f);
      }
    }
  }
}

// out[tok] += p * (h[assign] @ W2[e] + b2[e]);  N = DDIM, K = HDIM
__global__ void __launch_bounds__(512, 2) gemm2_kernel(
    const bf16_t* __restrict__ h, const bf16_t* __restrict__ W2t,
    const float* __restrict__ b2, const int* __restrict__ btok,
    const float* __restrict__ bprob, const int* __restrict__ offsets,
    const int* __restrict__ counts, const int* __restrict__ tmap,
    float* __restrict__ out) {
  const int tidx = blockIdx.y;
  if (tidx >= tmap[2 * MAX_MT]) return;
  const int e = tmap[tidx];
  const int m0 = tmap[MAX_MT + tidx];
  const int cnt = counts[e];
  const int aoff = offsets[e];
  const int n0 = blockIdx.x * 256;

  __shared__ __align__(16) bf16_t Al[256 * 32];
  __shared__ __align__(16) bf16_t Bl[256 * 32];

  const int tid = threadIdx.x;
  const int wave = tid >> 6;
  const int lane = tid & 63;

  const bf16_t* asrc[2];
  const bf16_t* bsrc[2];
#pragma unroll
  for (int j = 0; j < 2; ++j) {
    const int c = j * 512 + tid;
    const int r = c >> 2;
    const int kc = (c & 3) * 8;
    int arow = m0 + r;
    if (arow > cnt - 1) arow = cnt - 1;
    asrc[j] = h + (size_t)(aoff + arow) * HDIM + kc;
    bsrc[j] = W2t + ((size_t)e * DDIM + n0 + r) * HDIM + kc;
  }
  char* AlB = (char*)Al + wave * 1024;
  char* BlB = (char*)Bl + wave * 1024;

  f32x4 acc[8][4];
#pragma unroll
  for (int mf = 0; mf < 8; ++mf)
#pragma unroll
    for (int nf = 0; nf < 4; ++nf) acc[mf][nf] = (f32x4){0.f, 0.f, 0.f, 0.f};

  const int wr = (wave >> 2) * 128;
  const int wc = (wave & 3) * 64;
  const int lrow = lane & 15;
  const int lk = (lane >> 4) * 8;

  for (int k0 = 0; k0 < HDIM; k0 += 32) {
    GLOAD16(asrc[0] + k0, AlB);
    GLOAD16(asrc[1] + k0, AlB + 8192);
    GLOAD16(bsrc[0] + k0, BlB);
    GLOAD16(bsrc[1] + k0, BlB + 8192);
    __syncthreads();
    bf16x8 af[8], bfr[4];
#pragma unroll
    for (int mf = 0; mf < 8; ++mf)
      af[mf] = *(const bf16x8*)&Al[(wr + mf * 16 + lrow) * 32 + lk];
#pragma unroll
    for (int nf = 0; nf < 4; ++nf)
      bfr[nf] = *(const bf16x8*)&Bl[(wc + nf * 16 + lrow) * 32 + lk];
#pragma unroll
    for (int mf = 0; mf < 8; ++mf)
#pragma unroll
      for (int nf = 0; nf < 4; ++nf)
        acc[mf][nf] = __builtin_amdgcn_mfma_f32_16x16x32_bf16(
            af[mf], bfr[nf], acc[mf][nf], 0, 0, 0);
    __syncthreads();
  }

  // epilogue: out[tok] += p * (acc + b2)   (2 commutative atomics per element)
  const int rbase = (lane >> 4) * 4;
  const float* b2e = b2 + (size_t)e * DDIM + n0;
  float bb[4];
#pragma unroll
  for (int nf = 0; nf < 4; ++nf) bb[nf] = b2e[wc + nf * 16 + lrow];
#pragma unroll
  for (int mf = 0; mf < 8; ++mf) {
#pragma unroll
    for (int r = 0; r < 4; ++r) {
      const int grow = wr + mf * 16 + rbase + r;
      if (m0 + grow < cnt) {
        const int assign = aoff + m0 + grow;
        const int tok = btok[assign];
        const float p = bprob[assign];
        float* orow = out + (size_t)tok * DDIM + n0;
#pragma unroll
        for (int nf = 0; nf < 4; ++nf) {
          const int cl = wc + nf * 16 + lrow;
          atomicAdd(&orow[cl], (acc[mf][nf][r] + bb[nf]) * p);
        }
      }
    }
  }
}

// ---------------- launch ----------------

extern "C" void kernel_launch(void* const* d_in, const int* in_sizes, int n_in,
                              void* d_out, int out_size, void* d_ws,
                              size_t ws_size, hipStream_t stream) {
  const float* x = (const float*)d_in[0];
  const float* Wr = (const float*)d_in[1];
  const float* br = (const float*)d_in[2];
  const float* W1 = (const float*)d_in[3];
  const float* b1 = (const float*)d_in[4];
  const float* W2 = (const float*)d_in[5];
  const float* b2 = (const float*)d_in[6];
  // d_in[7] = k (fixed 2, hardcoded)

  char* w = (char*)d_ws;
  auto alloc = [&](size_t bytes) -> char* {
    char* p = w;
    w += (bytes + 255) & ~(size_t)255;
    return p;
  };
  bf16_t* xb = (bf16_t*)alloc((size_t)NTOK * DDIM * 2);
  bf16_t* W1t = (bf16_t*)alloc((size_t)NEXP * DDIM * HDIM * 2);
  bf16_t* W2t = (bf16_t*)alloc((size_t)NEXP * DDIM * HDIM * 2);
  bf16_t* hbuf = (bf16_t*)alloc((size_t)NASSIGN * HDIM * 2);
  int* btok = (int*)alloc(NASSIGN * 4);
  float* bprob = (float*)alloc(NASSIGN * 4);
  int2* ids = (int2*)alloc(NTOK * 8);
  float2* prs = (float2*)alloc(NTOK * 8);
  int* ctrl = (int*)alloc(64);     // counts[8] + cursor[8]
  int* offsets = (int*)alloc(64);  // 9 used
  int* tmap = (int*)alloc((2 * MAX_MT + 1) * 4);
  int* counts = ctrl;
  int* cursor = ctrl + 8;
  (void)in_sizes; (void)n_in; (void)ws_size;

  float* out = (float*)d_out;

  hipMemsetAsync(d_out, 0, (size_t)out_size * 4, stream);  // atomics target
  hipMemsetAsync(ctrl, 0, 64, stream);

  cvt_x_kernel<<<NTOK * DDIM / 2048, 256, 0, stream>>>(x, xb);
  transpose_cvt_kernel<<<dim3(HDIM / 32, DDIM / 32, NEXP), dim3(32, 8), 0,
                         stream>>>(W1, W1t, DDIM, HDIM);
  transpose_cvt_kernel<<<dim3(DDIM / 32, HDIM / 32, NEXP), dim3(32, 8), 0,
                         stream>>>(W2, W2t, HDIM, DDIM);
  router_kernel<<<NTOK, 256, 0, stream>>>(x, Wr, br, ids, prs, counts);
  scan_aux_kernel<<<1, 256, 0, stream>>>(counts, offsets, tmap, ids, prs,
                                         out + (size_t)NTOK * DDIM);
  scatter_kernel<<<NTOK / 256, 256, 0, stream>>>(ids, prs, offsets, cursor,
                                                 btok, bprob);
  gemm1_kernel<<<dim3(HDIM / 256, MAX_MT, 1), 512, 0, stream>>>(
      xb, W1t, b1, btok, offsets, counts, tmap, hbuf);
  gemm2_kernel<<<dim3(DDIM / 256, MAX_MT, 1), 512, 0, stream>>>(
      hbuf, W2t, b2, btok, bprob, offsets, counts, tmap, out);
}

// Round 3
// 1014.796 us; speedup vs baseline: 1.0051x; 1.0051x over previous
//
#include <hip/hip_runtime.h>
#include <hip/hip_bf16.h>

// MoE: N=8192 tokens, D=1024, H=4096, E=8 experts, top-k=2.
// Sparse grouped-GEMM: 256x256x64 tiles, 8 waves, DOUBLE-buffered LDS,
// T3-minimum 2-phase schedule (prefetch next K-tile before MFMA of current).

#define NTOK 8192
#define DDIM 1024
#define HDIM 4096
#define NEXP 8
#define NASSIGN (NTOK * 2)   // 16384 (token, expert) assignments
#define MAX_MT 72            // max ceil-sum of per-expert 256-row tiles
#define KSPLIT 4             // gemm2 K-split (4096 -> 4 x 1024)

typedef __bf16 bf16_t;
typedef __bf16 bf16x4 __attribute__((ext_vector_type(4)));
typedef __bf16 bf16x8 __attribute__((ext_vector_type(8)));
typedef float f32x4 __attribute__((ext_vector_type(4)));

// async global->LDS, 16B per lane; LDS dest = wave-uniform base + lane*16
#define GLOAD16(gptr, lptr)                                                    \
  __builtin_amdgcn_global_load_lds(                                            \
      (const __attribute__((address_space(1))) void*)(gptr),                   \
      (__attribute__((address_space(3))) void*)(lptr), 16, 0, 0)

// ---------------- weight transpose: [E][R][C] f32 -> [E][C][R] bf16 --------

__global__ void __launch_bounds__(256) transpose_cvt_kernel(
    const float* __restrict__ in, bf16_t* __restrict__ out, int R, int C) {
  __shared__ float tile[32][33];
  const size_t mat = (size_t)R * C;
  const float* ip = in + (size_t)blockIdx.z * mat;
  bf16_t* op = out + (size_t)blockIdx.z * mat;
  const int c0 = blockIdx.x * 32, r0 = blockIdx.y * 32;
  const int tx = threadIdx.x, ty = threadIdx.y;  // (32, 8)
#pragma unroll
  for (int i = 0; i < 4; ++i) {
    const int r = ty + 8 * i;
    tile[r][tx] = ip[(size_t)(r0 + r) * C + (c0 + tx)];
  }
  __syncthreads();
#pragma unroll
  for (int i = 0; i < 4; ++i) {
    const int r = ty + 8 * i;
    op[(size_t)(c0 + r) * R + (r0 + tx)] = (bf16_t)tile[tx][r];
  }
}

// ---------------- router (fused x -> bf16 conversion) ----------------------

__global__ void __launch_bounds__(256) router_kernel(
    const float* __restrict__ x, const float* __restrict__ Wr,
    const float* __restrict__ br, int2* __restrict__ ids,
    float2* __restrict__ prs, int* __restrict__ counts,
    bf16_t* __restrict__ xb) {
  const int n = blockIdx.x;
  const int t = threadIdx.x;
  const float4 xv = ((const float4*)(x + (size_t)n * DDIM))[t];
  // fused bf16 conversion of x
  bf16x4 o;
  o[0] = (bf16_t)xv.x; o[1] = (bf16_t)xv.y;
  o[2] = (bf16_t)xv.z; o[3] = (bf16_t)xv.w;
  ((bf16x4*)(xb + (size_t)n * DDIM))[t] = o;

  float acc[NEXP];
#pragma unroll
  for (int e = 0; e < NEXP; ++e) acc[e] = 0.f;
  const float xq[4] = {xv.x, xv.y, xv.z, xv.w};
#pragma unroll
  for (int q = 0; q < 4; ++q) {
    const float* w = Wr + (size_t)(4 * t + q) * NEXP;
#pragma unroll
    for (int e = 0; e < NEXP; ++e) acc[e] += xq[q] * w[e];
  }
  __shared__ float red[256][NEXP];
#pragma unroll
  for (int e = 0; e < NEXP; ++e) red[t][e] = acc[e];
  __syncthreads();
  for (int s = 128; s >= 1; s >>= 1) {  // fixed tree -> deterministic logits
    if (t < s) {
#pragma unroll
      for (int e = 0; e < NEXP; ++e) red[t][e] += red[t + s][e];
    }
    __syncthreads();
  }
  if (t == 0) {
    float l[NEXP];
#pragma unroll
    for (int e = 0; e < NEXP; ++e) l[e] = red[0][e] + br[e];
    int i1 = 0; float v1 = l[0];
    for (int e = 1; e < NEXP; ++e)
      if (l[e] > v1) { v1 = l[e]; i1 = e; }
    int i2 = (i1 == 0) ? 1 : 0; float v2 = l[i2];
    for (int e = 0; e < NEXP; ++e)
      if (e != i1 && l[e] > v2) { v2 = l[e]; i2 = e; }
    float denom = 0.f;
    for (int e = 0; e < NEXP; ++e) denom += expf(l[e] - v1);
    const float p1 = 1.f / denom;
    const float p2 = expf(v2 - v1) / denom;
    ids[n] = make_int2(i1, i2);
    prs[n] = make_float2(p1, p2);
    atomicAdd(&counts[i1], 1);
    atomicAdd(&counts[i2], 1);
  }
}

// scan (thread 0) + aux loss (all 256 threads), one kernel
__global__ void __launch_bounds__(256) scan_aux_kernel(
    const int* __restrict__ counts, int* __restrict__ offsets,
    int* __restrict__ tmap, const int2* __restrict__ ids,
    const float2* __restrict__ prs, float* __restrict__ aux_out) {
  const int t = threadIdx.x;
  if (t == 0) {
    int off = 0, nt = 0;
    for (int e = 0; e < NEXP; ++e) {
      offsets[e] = off;
      const int c = counts[e];
      for (int m0 = 0; m0 < c; m0 += 256) {
        tmap[nt] = e;
        tmap[MAX_MT + nt] = m0;
        ++nt;
      }
      off += c;
    }
    offsets[NEXP] = off;
    tmap[2 * MAX_MT] = nt;
  }
  float imp[NEXP];
#pragma unroll
  for (int e = 0; e < NEXP; ++e) imp[e] = 0.f;
  for (int n = t; n < NTOK; n += 256) {
    const int2 id = ids[n];
    const float2 pr = prs[n];
#pragma unroll
    for (int e = 0; e < NEXP; ++e)
      imp[e] += (id.x == e ? pr.x : 0.f) + (id.y == e ? pr.y : 0.f);
  }
  __shared__ float red[256][NEXP];
#pragma unroll
  for (int e = 0; e < NEXP; ++e) red[t][e] = imp[e];
  __syncthreads();
  for (int s = 128; s >= 1; s >>= 1) {
    if (t < s) {
#pragma unroll
      for (int e = 0; e < NEXP; ++e) red[t][e] += red[t + s][e];
    }
    __syncthreads();
  }
  if (t == 0) {
    float m = 0.f;
    for (int e = 0; e < NEXP; ++e) m += red[0][e];
    m *= (1.f / NEXP);
    float v = 0.f;
    for (int e = 0; e < NEXP; ++e) {
      const float d = red[0][e] - m;
      v += d * d;
    }
    v *= (1.f / (NEXP - 1));  // ddof=1
    aux_out[0] = v / (m * m + 1e-9f);
  }
}

__global__ void __launch_bounds__(256) scatter_kernel(
    const int2* __restrict__ ids, const float2* __restrict__ prs,
    const int* __restrict__ offsets, int* __restrict__ cursor,
    int* __restrict__ btok, float* __restrict__ bprob) {
  const int n = blockIdx.x * 256 + threadIdx.x;
  if (n >= NTOK) return;
  const int2 id = ids[n];
  const float2 pr = prs[n];
  int p = atomicAdd(&cursor[id.x], 1);
  btok[offsets[id.x] + p] = n;
  bprob[offsets[id.x] + p] = pr.x;
  p = atomicAdd(&cursor[id.y], 1);
  btok[offsets[id.y] + p] = n;
  bprob[offsets[id.y] + p] = pr.y;
}

// ---------------- grouped GEMMs: 256x256, BK=64, 2-phase dbuf --------------
// 8 waves (2M x 4N); per-wave output 128x64 = acc[8][4] f32x4.
// LDS: 2 x (A[256][64] + B[256][64]) bf16 = 128 KiB.
// Staging: 8 x global_load_lds(16B)/thread per K-tile, issued BEFORE the
// MFMA of the current tile; one vmcnt(0)+barrier per K-tile (__syncthreads).

// h[assign, :] = relu(x[btok[assign]] @ W1[e] + b1[e]);  N = HDIM, K = DDIM
__global__ void __launch_bounds__(512, 2) gemm1_kernel(
    const bf16_t* __restrict__ xb, const bf16_t* __restrict__ W1t,
    const float* __restrict__ b1, const int* __restrict__ btok,
    const int* __restrict__ offsets, const int* __restrict__ counts,
    const int* __restrict__ tmap, bf16_t* __restrict__ h) {
  const int tidx = blockIdx.y;
  if (tidx >= tmap[2 * MAX_MT]) return;
  const int e = tmap[tidx];
  const int m0 = tmap[MAX_MT + tidx];
  const int cnt = counts[e];
  const int aoff = offsets[e];
  const int n0 = blockIdx.x * 256;

  __shared__ __align__(16) bf16_t Al[2][256 * 64];  // 2 x 32 KB
  __shared__ __align__(16) bf16_t Bl[2][256 * 64];  // 2 x 32 KB

  const int tid = threadIdx.x;
  const int wave = tid >> 6;
  const int lane = tid & 63;

  // per-thread global source bases: 4 chunks each for A and B
  const bf16_t* asrc[4];
  const bf16_t* bsrc[4];
#pragma unroll
  for (int j = 0; j < 4; ++j) {
    const int c = j * 512 + tid;   // 16B-chunk index [0,2048)
    const int r = c >> 3;          // tile row (8 chunks per 128B row)
    const int kc = (c & 7) * 8;    // k element offset
    int arow = m0 + r;
    if (arow > cnt - 1) arow = cnt - 1;  // clamp (stores masked later)
    asrc[j] = xb + (size_t)btok[aoff + arow] * DDIM + kc;
    bsrc[j] = W1t + ((size_t)e * HDIM + n0 + r) * DDIM + kc;
  }

  f32x4 acc[8][4];
#pragma unroll
  for (int mf = 0; mf < 8; ++mf)
#pragma unroll
    for (int nf = 0; nf < 4; ++nf) acc[mf][nf] = (f32x4){0.f, 0.f, 0.f, 0.f};

  const int wr = (wave >> 2) * 128;
  const int wc = (wave & 3) * 64;
  const int lrow = lane & 15;
  const int lk8 = (lane >> 4) * 8;

  auto stage = [&](int b, int t) {
    const int ko = t * 64;
    char* Ab = (char*)&Al[b][0] + wave * 1024;
    char* Bb = (char*)&Bl[b][0] + wave * 1024;
#pragma unroll
    for (int j = 0; j < 4; ++j) {
      GLOAD16(asrc[j] + ko, Ab + j * 8192);
      GLOAD16(bsrc[j] + ko, Bb + j * 8192);
    }
  };
  auto compute = [&](int b) {
    const bf16_t* Ab = &Al[b][0];
    const bf16_t* Bb = &Bl[b][0];
    __builtin_amdgcn_s_setprio(1);
#pragma unroll
    for (int ks = 0; ks < 2; ++ks) {
      bf16x8 af[8], bfr[4];
#pragma unroll
      for (int mf = 0; mf < 8; ++mf)
        af[mf] = *(const bf16x8*)&Ab[(wr + mf * 16 + lrow) * 64 + ks * 32 + lk8];
#pragma unroll
      for (int nf = 0; nf < 4; ++nf)
        bfr[nf] = *(const bf16x8*)&Bb[(wc + nf * 16 + lrow) * 64 + ks * 32 + lk8];
#pragma unroll
      for (int mf = 0; mf < 8; ++mf)
#pragma unroll
        for (int nf = 0; nf < 4; ++nf)
          acc[mf][nf] = __builtin_amdgcn_mfma_f32_16x16x32_bf16(
              af[mf], bfr[nf], acc[mf][nf], 0, 0, 0);
    }
    __builtin_amdgcn_s_setprio(0);
  };

  // 2-phase pipeline over NT = DDIM/64 = 16 K-tiles
  stage(0, 0);
  __syncthreads();
#pragma unroll
  for (int t = 0; t < 16; t += 2) {
    stage(1, t + 1);
    compute(0);
    __syncthreads();
    if (t + 2 < 16) stage(0, t + 2);
    compute(1);
    __syncthreads();
  }

  // epilogue: h = relu(acc + b1), bf16
  const int rbase = (lane >> 4) * 4;
  const float* b1e = b1 + (size_t)e * HDIM + n0;
#pragma unroll
  for (int nf = 0; nf < 4; ++nf) {
    const int cl = wc + nf * 16 + lrow;
    const float bb = b1e[cl];
#pragma unroll
    for (int mf = 0; mf < 8; ++mf) {
#pragma unroll
      for (int r = 0; r < 4; ++r) {
        const int grow = wr + mf * 16 + rbase + r;
        if (m0 + grow < cnt)
          h[(size_t)(aoff + m0 + grow) * HDIM + (n0 + cl)] =
              (bf16_t)fmaxf(acc[mf][nf][r] + bb, 0.f);
      }
    }
  }
}

// out[tok] += p * (h[assign] @ W2[e] + b2[e]);  N = DDIM, K-split over HDIM
__global__ void __launch_bounds__(512, 2) gemm2_kernel(
    const bf16_t* __restrict__ h, const bf16_t* __restrict__ W2t,
    const float* __restrict__ b2, const int* __restrict__ btok,
    const float* __restrict__ bprob, const int* __restrict__ offsets,
    const int* __restrict__ counts, const int* __restrict__ tmap,
    float* __restrict__ out) {
  const int tidx = blockIdx.y >> 2;       // m-tile
  const int kch = blockIdx.y & 3;         // K chunk: [kch*1024, +1024)
  if (tidx >= tmap[2 * MAX_MT]) return;
  const int e = tmap[tidx];
  const int m0 = tmap[MAX_MT + tidx];
  const int cnt = counts[e];
  const int aoff = offsets[e];
  const int n0 = blockIdx.x * 256;

  __shared__ __align__(16) bf16_t Al[2][256 * 64];
  __shared__ __align__(16) bf16_t Bl[2][256 * 64];

  const int tid = threadIdx.x;
  const int wave = tid >> 6;
  const int lane = tid & 63;

  const bf16_t* asrc[4];
  const bf16_t* bsrc[4];
#pragma unroll
  for (int j = 0; j < 4; ++j) {
    const int c = j * 512 + tid;
    const int r = c >> 3;
    const int kc = (c & 7) * 8 + kch * 1024;
    int arow = m0 + r;
    if (arow > cnt - 1) arow = cnt - 1;
    asrc[j] = h + (size_t)(aoff + arow) * HDIM + kc;
    bsrc[j] = W2t + ((size_t)e * DDIM + n0 + r) * HDIM + kc;
  }

  f32x4 acc[8][4];
#pragma unroll
  for (int mf = 0; mf < 8; ++mf)
#pragma unroll
    for (int nf = 0; nf < 4; ++nf) acc[mf][nf] = (f32x4){0.f, 0.f, 0.f, 0.f};

  const int wr = (wave >> 2) * 128;
  const int wc = (wave & 3) * 64;
  const int lrow = lane & 15;
  const int lk8 = (lane >> 4) * 8;

  auto stage = [&](int b, int t) {
    const int ko = t * 64;
    char* Ab = (char*)&Al[b][0] + wave * 1024;
    char* Bb = (char*)&Bl[b][0] + wave * 1024;
#pragma unroll
    for (int j = 0; j < 4; ++j) {
      GLOAD16(asrc[j] + ko, Ab + j * 8192);
      GLOAD16(bsrc[j] + ko, Bb + j * 8192);
    }
  };
  auto compute = [&](int b) {
    const bf16_t* Ab = &Al[b][0];
    const bf16_t* Bb = &Bl[b][0];
    __builtin_amdgcn_s_setprio(1);
#pragma unroll
    for (int ks = 0; ks < 2; ++ks) {
      bf16x8 af[8], bfr[4];
#pragma unroll
      for (int mf = 0; mf < 8; ++mf)
        af[mf] = *(const bf16x8*)&Ab[(wr + mf * 16 + lrow) * 64 + ks * 32 + lk8];
#pragma unroll
      for (int nf = 0; nf < 4; ++nf)
        bfr[nf] = *(const bf16x8*)&Bb[(wc + nf * 16 + lrow) * 64 + ks * 32 + lk8];
#pragma unroll
      for (int mf = 0; mf < 8; ++mf)
#pragma unroll
        for (int nf = 0; nf < 4; ++nf)
          acc[mf][nf] = __builtin_amdgcn_mfma_f32_16x16x32_bf16(
              af[mf], bfr[nf], acc[mf][nf], 0, 0, 0);
    }
    __builtin_amdgcn_s_setprio(0);
  };

  stage(0, 0);
  __syncthreads();
#pragma unroll
  for (int t = 0; t < 16; t += 2) {
    stage(1, t + 1);
    compute(0);
    __syncthreads();
    if (t + 2 < 16) stage(0, t + 2);
    compute(1);
    __syncthreads();
  }

  // epilogue: out[tok] += p * (acc + b2)  (commutative f32 atomics; bias
  // contributed only by the kch==0 block)
  const int rbase = (lane >> 4) * 4;
  const float* b2e = b2 + (size_t)e * DDIM + n0;
  float bb[4];
#pragma unroll
  for (int nf = 0; nf < 4; ++nf)
    bb[nf] = (kch == 0) ? b2e[wc + nf * 16 + lrow] : 0.f;
#pragma unroll
  for (int mf = 0; mf < 8; ++mf) {
#pragma unroll
    for (int r = 0; r < 4; ++r) {
      const int grow = wr + mf * 16 + rbase + r;
      if (m0 + grow < cnt) {
        const int assign = aoff + m0 + grow;
        const int tok = btok[assign];
        const float p = bprob[assign];
        float* orow = out + (size_t)tok * DDIM + n0;
#pragma unroll
        for (int nf = 0; nf < 4; ++nf) {
          const int cl = wc + nf * 16 + lrow;
          atomicAdd(&orow[cl], (acc[mf][nf][r] + bb[nf]) * p);
        }
      }
    }
  }
}

// ---------------- launch ----------------

extern "C" void kernel_launch(void* const* d_in, const int* in_sizes, int n_in,
                              void* d_out, int out_size, void* d_ws,
                              size_t ws_size, hipStream_t stream) {
  const float* x = (const float*)d_in[0];
  const float* Wr = (const float*)d_in[1];
  const float* br = (const float*)d_in[2];
  const float* W1 = (const float*)d_in[3];
  const float* b1 = (const float*)d_in[4];
  const float* W2 = (const float*)d_in[5];
  const float* b2 = (const float*)d_in[6];
  // d_in[7] = k (fixed 2, hardcoded)

  char* w = (char*)d_ws;
  auto alloc = [&](size_t bytes) -> char* {
    char* p = w;
    w += (bytes + 255) & ~(size_t)255;
    return p;
  };
  bf16_t* xb = (bf16_t*)alloc((size_t)NTOK * DDIM * 2);
  bf16_t* W1t = (bf16_t*)alloc((size_t)NEXP * DDIM * HDIM * 2);
  bf16_t* W2t = (bf16_t*)alloc((size_t)NEXP * DDIM * HDIM * 2);
  bf16_t* hbuf = (bf16_t*)alloc((size_t)NASSIGN * HDIM * 2);
  int* btok = (int*)alloc(NASSIGN * 4);
  float* bprob = (float*)alloc(NASSIGN * 4);
  int2* ids = (int2*)alloc(NTOK * 8);
  float2* prs = (float2*)alloc(NTOK * 8);
  int* ctrl = (int*)alloc(64);     // counts[8] + cursor[8]
  int* offsets = (int*)alloc(64);  // 9 used
  int* tmap = (int*)alloc((2 * MAX_MT + 1) * 4);
  int* counts = ctrl;
  int* cursor = ctrl + 8;
  (void)in_sizes; (void)n_in; (void)ws_size;

  float* out = (float*)d_out;

  hipMemsetAsync(d_out, 0, (size_t)out_size * 4, stream);  // atomics target
  hipMemsetAsync(ctrl, 0, 64, stream);

  transpose_cvt_kernel<<<dim3(HDIM / 32, DDIM / 32, NEXP), dim3(32, 8), 0,
                         stream>>>(W1, W1t, DDIM, HDIM);
  transpose_cvt_kernel<<<dim3(DDIM / 32, HDIM / 32, NEXP), dim3(32, 8), 0,
                         stream>>>(W2, W2t, HDIM, DDIM);
  router_kernel<<<NTOK, 256, 0, stream>>>(x, Wr, br, ids, prs, counts, xb);
  scan_aux_kernel<<<1, 256, 0, stream>>>(counts, offsets, tmap, ids, prs,
                                         out + (size_t)NTOK * DDIM);
  scatter_kernel<<<NTOK / 256, 256, 0, stream>>>(ids, prs, offsets, cursor,
                                                 btok, bprob);
  gemm1_kernel<<<dim3(HDIM / 256, MAX_MT, 1), 512, 0, stream>>>(
      xb, W1t, b1, btok, offsets, counts, tmap, hbuf);
  gemm2_kernel<<<dim3(DDIM / 256, MAX_MT * KSPLIT, 1), 512, 0, stream>>>(
      hbuf, W2t, b2, btok, bprob, offsets, counts, tmap, out);
}

// Round 5
// 941.268 us; speedup vs baseline: 1.0836x; 1.0781x over previous
//
#include <hip/hip_runtime.h>
#include <hip/hip_bf16.h>

// MoE: N=8192 tokens, D=1024, H=4096, E=8 experts, top-k=2.
// Grouped GEMMs: 128x128 tile, BK=32, 3-deep circular LDS buffer,
// counted vmcnt(4) + raw s_barrier (1 barrier/K-step), XOR bank swizzle.

#define NTOK 8192
#define DDIM 1024
#define HDIM 4096
#define NEXP 8
#define NASSIGN (NTOK * 2)
#define MAX_MT 135              // max ceil-sum of per-expert 128-row tiles
#define GRID1 (32 * MAX_MT)     // 4320, divisible by 8
#define GRID2 (8 * 4 * MAX_MT)  // 4320, divisible by 8

typedef __bf16 bf16_t;
typedef __bf16 bf16x2 __attribute__((ext_vector_type(2)));
typedef __bf16 bf16x4 __attribute__((ext_vector_type(4)));
typedef __bf16 bf16x8 __attribute__((ext_vector_type(8)));
typedef float f32x4 __attribute__((ext_vector_type(4)));

#define GLOAD16(gptr, lptr)                                                    \
  __builtin_amdgcn_global_load_lds(                                            \
      (const __attribute__((address_space(1))) void*)(gptr),                   \
      (__attribute__((address_space(3))) void*)(lptr), 16, 0, 0)

#define VMCNT(n) asm volatile("s_waitcnt vmcnt(" #n ")" ::: "memory")

// bijective XCD swizzle: launched id -> logical job; nwg % 8 == 0
__device__ __forceinline__ int xcd_swz(int orig, int nwg) {
  const int cpx = nwg >> 3;
  return (orig & 7) * cpx + (orig >> 3);
}

// ---------------- weight transpose: [E][R][C] f32 -> [E][C][R] bf16 --------
// tile 64(R) x 32(C); fully coalesced reads (128B) and writes (128B).
__global__ void __launch_bounds__(256) transpose_cvt_kernel(
    const float* __restrict__ in, bf16_t* __restrict__ out, int R, int C) {
  __shared__ float tile[64][33];
  const size_t mat = (size_t)R * C;
  const float* ip = in + (size_t)blockIdx.z * mat;
  bf16_t* op = out + (size_t)blockIdx.z * mat;
  const int c0 = blockIdx.x * 32, r0 = blockIdx.y * 64;
  const int tx = threadIdx.x, ty = threadIdx.y;  // (32, 8)
#pragma unroll
  for (int i = 0; i < 8; ++i) {
    const int r = ty + 8 * i;
    tile[r][tx] = ip[(size_t)(r0 + r) * C + (c0 + tx)];
  }
  __syncthreads();
#pragma unroll
  for (int j = 0; j < 4; ++j) {
    const int c = ty + 8 * j;
    bf16x2 v;
    v[0] = (bf16_t)tile[2 * tx][c];
    v[1] = (bf16_t)tile[2 * tx + 1][c];
    *(bf16x2*)(op + (size_t)(c0 + c) * R + r0 + 2 * tx) = v;
  }
}

// ---------------- router (fused x -> bf16; wave-shuffle reduce) ------------
__global__ void __launch_bounds__(256) router_kernel(
    const float* __restrict__ x, const float* __restrict__ Wr,
    const float* __restrict__ br, int2* __restrict__ ids,
    float2* __restrict__ prs, int* __restrict__ counts,
    bf16_t* __restrict__ xb) {
  const int n = blockIdx.x;
  const int t = threadIdx.x;
  const int wave = t >> 6, lane = t & 63;
  const float4 xv = ((const float4*)(x + (size_t)n * DDIM))[t];
  bf16x4 o;
  o[0] = (bf16_t)xv.x; o[1] = (bf16_t)xv.y;
  o[2] = (bf16_t)xv.z; o[3] = (bf16_t)xv.w;
  ((bf16x4*)(xb + (size_t)n * DDIM))[t] = o;

  float acc[NEXP];
#pragma unroll
  for (int e = 0; e < NEXP; ++e) acc[e] = 0.f;
  const float xq[4] = {xv.x, xv.y, xv.z, xv.w};
#pragma unroll
  for (int q = 0; q < 4; ++q) {
    const float* w = Wr + (size_t)(4 * t + q) * NEXP;
#pragma unroll
    for (int e = 0; e < NEXP; ++e) acc[e] += xq[q] * w[e];
  }
  // fixed-tree wave reduce (deterministic)
#pragma unroll
  for (int off = 32; off >= 1; off >>= 1)
#pragma unroll
    for (int e = 0; e < NEXP; ++e) acc[e] += __shfl_down(acc[e], off);
  __shared__ float red[4][NEXP];
  if (lane == 0)
#pragma unroll
    for (int e = 0; e < NEXP; ++e) red[wave][e] = acc[e];
  __syncthreads();
  if (t == 0) {
    float l[NEXP];
#pragma unroll
    for (int e = 0; e < NEXP; ++e)
      l[e] = ((red[0][e] + red[1][e]) + (red[2][e] + red[3][e])) + br[e];
    int i1 = 0; float v1 = l[0];
    for (int e = 1; e < NEXP; ++e)
      if (l[e] > v1) { v1 = l[e]; i1 = e; }
    int i2 = (i1 == 0) ? 1 : 0; float v2 = l[i2];
    for (int e = 0; e < NEXP; ++e)
      if (e != i1 && l[e] > v2) { v2 = l[e]; i2 = e; }
    float denom = 0.f;
    for (int e = 0; e < NEXP; ++e) denom += expf(l[e] - v1);
    ids[n] = make_int2(i1, i2);
    prs[n] = make_float2(1.f / denom, expf(v2 - v1) / denom);
    atomicAdd(&counts[i1], 1);
    atomicAdd(&counts[i2], 1);
  }
}

// scan (thread 0) + aux loss
__global__ void __launch_bounds__(256) scan_aux_kernel(
    const int* __restrict__ counts, int* __restrict__ offsets,
    int* __restrict__ tmap, const int2* __restrict__ ids,
    const float2* __restrict__ prs, float* __restrict__ aux_out) {
  const int t = threadIdx.x;
  if (t == 0) {
    int off = 0, nt = 0;
    for (int e = 0; e < NEXP; ++e) {
      offsets[e] = off;
      const int c = counts[e];
      for (int m0 = 0; m0 < c; m0 += 128) {
        tmap[nt] = e;
        tmap[MAX_MT + nt] = m0;
        ++nt;
      }
      off += c;
    }
    offsets[NEXP] = off;
    tmap[2 * MAX_MT] = nt;
  }
  float imp[NEXP];
#pragma unroll
  for (int e = 0; e < NEXP; ++e) imp[e] = 0.f;
  for (int n = t; n < NTOK; n += 256) {
    const int2 id = ids[n];
    const float2 pr = prs[n];
#pragma unroll
    for (int e = 0; e < NEXP; ++e)
      imp[e] += (id.x == e ? pr.x : 0.f) + (id.y == e ? pr.y : 0.f);
  }
  __shared__ float red[256][NEXP];
#pragma unroll
  for (int e = 0; e < NEXP; ++e) red[t][e] = imp[e];
  __syncthreads();
  for (int s = 128; s >= 1; s >>= 1) {
    if (t < s) {
#pragma unroll
      for (int e = 0; e < NEXP; ++e) red[t][e] += red[t + s][e];
    }
    __syncthreads();
  }
  if (t == 0) {
    float m = 0.f;
    for (int e = 0; e < NEXP; ++e) m += red[0][e];
    m *= (1.f / NEXP);
    float v = 0.f;
    for (int e = 0; e < NEXP; ++e) {
      const float d = red[0][e] - m;
      v += d * d;
    }
    v *= (1.f / (NEXP - 1));  // ddof=1
    aux_out[0] = v / (m * m + 1e-9f);
  }
}

__global__ void __launch_bounds__(256) scatter_kernel(
    const int2* __restrict__ ids, const float2* __restrict__ prs,
    const int* __restrict__ offsets, int* __restrict__ cursor,
    int* __restrict__ btok, float* __restrict__ bprob) {
  const int n = blockIdx.x * 256 + threadIdx.x;
  if (n >= NTOK) return;
  const int2 id = ids[n];
  const float2 pr = prs[n];
  int p = atomicAdd(&cursor[id.x], 1);
  btok[offsets[id.x] + p] = n;
  bprob[offsets[id.x] + p] = pr.x;
  p = atomicAdd(&cursor[id.y], 1);
  btok[offsets[id.y] + p] = n;
  bprob[offsets[id.y] + p] = pr.y;
}

// ---------------- grouped GEMMs: 128x128, BK=32, 3-buffer counted pipeline --
// Per K-step (per wave): vmcnt(4) -> s_barrier -> stage tile t+2 (4 loads)
// -> 8 ds_read_b128 (XOR-swizzled, 2-way = free) -> 16 MFMA.
// Swizzle: physical 16B slot = logical ^ ((row>>1)&3), applied identically
// to the global source (pre-swizzle) and the LDS read (rule #21).

// h[assign, :] = relu(x[btok[assign]] @ W1[e] + b1[e]);  N = HDIM, K = DDIM
__global__ void __launch_bounds__(256, 3) gemm1_kernel(
    const bf16_t* __restrict__ xb, const bf16_t* __restrict__ W1t,
    const float* __restrict__ b1, const int* __restrict__ btok,
    const int* __restrict__ offsets, const int* __restrict__ counts,
    const int* __restrict__ tmap, bf16_t* __restrict__ h) {
  const int job = xcd_swz((int)blockIdx.x, GRID1);
  const int tidx = job >> 5;   // 32 n-blocks per m-tile
  const int nblk = job & 31;
  if (tidx >= tmap[2 * MAX_MT]) return;
  const int e = tmap[tidx];
  const int m0 = tmap[MAX_MT + tidx];
  const int cnt = counts[e];
  const int aoff = offsets[e];
  const int n0 = nblk * 128;

  __shared__ __align__(16) bf16_t Al[3][128 * 32];  // 3 x 8 KB
  __shared__ __align__(16) bf16_t Bl[3][128 * 32];  // 3 x 8 KB

  const int tid = threadIdx.x;
  const int wave = tid >> 6;
  const int lane = tid & 63;

  // staging sources (pre-swizzled 16B slot), fixed over K
  const bf16_t* asrc[2];
  const bf16_t* bsrc[2];
#pragma unroll
  for (int j = 0; j < 2; ++j) {
    const int c = j * 256 + tid;           // 16B chunk id [0,512)
    const int r = c >> 2;                  // tile row
    const int slot = (c & 3) ^ ((r >> 1) & 3);
    int arow = m0 + r;
    if (arow > cnt - 1) arow = cnt - 1;    // clamp (stores masked later)
    asrc[j] = xb + (size_t)btok[aoff + arow] * DDIM + slot * 8;
    bsrc[j] = W1t + ((size_t)e * HDIM + n0 + r) * DDIM + slot * 8;
  }

  const int wr = (wave >> 1) * 64;
  const int wc = (wave & 1) * 64;
  const int lrow = lane & 15;
  const int lslot = lane >> 4;

  // per-lane swizzled read offsets (bytes within a buffer)
  int aoffb[4], boffb[4];
#pragma unroll
  for (int f = 0; f < 4; ++f) {
    const int Rr = wr + f * 16 + lrow;
    aoffb[f] = Rr * 64 + ((lslot ^ ((Rr >> 1) & 3)) << 4);
    const int Cc = wc + f * 16 + lrow;
    boffb[f] = Cc * 64 + ((lslot ^ ((Cc >> 1) & 3)) << 4);
  }

  f32x4 acc[4][4];
#pragma unroll
  for (int mf = 0; mf < 4; ++mf)
#pragma unroll
    for (int nf = 0; nf < 4; ++nf) acc[mf][nf] = (f32x4){0.f, 0.f, 0.f, 0.f};

  auto stage = [&](int b, int t) {
    char* Ab = (char*)&Al[b][0] + wave * 1024;
    char* Bb = (char*)&Bl[b][0] + wave * 1024;
    const int ko = t * 32;
#pragma unroll
    for (int j = 0; j < 2; ++j) {
      GLOAD16(asrc[j] + ko, Ab + j * 4096);
      GLOAD16(bsrc[j] + ko, Bb + j * 4096);
    }
  };
  auto compute = [&](int b) {
    const char* Ab = (const char*)&Al[b][0];
    const char* Bb = (const char*)&Bl[b][0];
    bf16x8 af[4], bfr[4];
#pragma unroll
    for (int f = 0; f < 4; ++f) {
      af[f] = *(const bf16x8*)(Ab + aoffb[f]);
      bfr[f] = *(const bf16x8*)(Bb + boffb[f]);
    }
    __builtin_amdgcn_s_setprio(1);
#pragma unroll
    for (int mf = 0; mf < 4; ++mf)
#pragma unroll
      for (int nf = 0; nf < 4; ++nf)
        acc[mf][nf] = __builtin_amdgcn_mfma_f32_16x16x32_bf16(
            af[mf], bfr[nf], acc[mf][nf], 0, 0, 0);
    __builtin_amdgcn_s_setprio(0);
  };

  // K pipeline: NT = 32 tiles of BK=32
  stage(0, 0);
  stage(1, 1);
  int cb = 0, pb = 2;
  for (int t = 0; t < 31; ++t) {
    VMCNT(4);
    __builtin_amdgcn_s_barrier();
    __builtin_amdgcn_sched_barrier(0);
    if (t + 2 < 32) stage(pb, t + 2);
    compute(cb);
    cb = (cb == 2) ? 0 : cb + 1;
    pb = (pb == 2) ? 0 : pb + 1;
  }
  VMCNT(0);
  __builtin_amdgcn_s_barrier();
  __builtin_amdgcn_sched_barrier(0);
  compute(cb);

  // epilogue: h = relu(acc + b1), bf16
  const int rbase = (lane >> 4) * 4;
  const float* b1e = b1 + (size_t)e * HDIM + n0;
#pragma unroll
  for (int nf = 0; nf < 4; ++nf) {
    const int cl = wc + nf * 16 + lrow;
    const float bb = b1e[cl];
#pragma unroll
    for (int mf = 0; mf < 4; ++mf) {
#pragma unroll
      for (int r = 0; r < 4; ++r) {
        const int grow = wr + mf * 16 + rbase + r;
        if (m0 + grow < cnt)
          h[(size_t)(aoff + m0 + grow) * HDIM + (n0 + cl)] =
              (bf16_t)fmaxf(acc[mf][nf][r] + bb, 0.f);
      }
    }
  }
}

// out[tok] += p * (h[assign] @ W2[e] + b2[e]);  N = DDIM, K-split 4x1024
__global__ void __launch_bounds__(256, 3) gemm2_kernel(
    const bf16_t* __restrict__ h, const bf16_t* __restrict__ W2t,
    const float* __restrict__ b2, const int* __restrict__ btok,
    const float* __restrict__ bprob, const int* __restrict__ offsets,
    const int* __restrict__ counts, const int* __restrict__ tmap,
    float* __restrict__ out) {
  const int job = xcd_swz((int)blockIdx.x, GRID2);
  const int tidx = job >> 5;            // 8 n-blocks x 4 k-chunks per m-tile
  const int nblk = job & 7;
  const int kch = (job >> 3) & 3;
  if (tidx >= tmap[2 * MAX_MT]) return;
  const int e = tmap[tidx];
  const int m0 = tmap[MAX_MT + tidx];
  const int cnt = counts[e];
  const int aoff = offsets[e];
  const int n0 = nblk * 128;

  __shared__ __align__(16) bf16_t Al[3][128 * 32];
  __shared__ __align__(16) bf16_t Bl[3][128 * 32];

  const int tid = threadIdx.x;
  const int wave = tid >> 6;
  const int lane = tid & 63;

  const bf16_t* asrc[2];
  const bf16_t* bsrc[2];
#pragma unroll
  for (int j = 0; j < 2; ++j) {
    const int c = j * 256 + tid;
    const int r = c >> 2;
    const int slot = (c & 3) ^ ((r >> 1) & 3);
    int arow = m0 + r;
    if (arow > cnt - 1) arow = cnt - 1;
    asrc[j] = h + (size_t)(aoff + arow) * HDIM + kch * 1024 + slot * 8;
    bsrc[j] = W2t + ((size_t)e * DDIM + n0 + r) * HDIM + kch * 1024 + slot * 8;
  }

  const int wr = (wave >> 1) * 64;
  const int wc = (wave & 1) * 64;
  const int lrow = lane & 15;
  const int lslot = lane >> 4;

  int aoffb[4], boffb[4];
#pragma unroll
  for (int f = 0; f < 4; ++f) {
    const int Rr = wr + f * 16 + lrow;
    aoffb[f] = Rr * 64 + ((lslot ^ ((Rr >> 1) & 3)) << 4);
    const int Cc = wc + f * 16 + lrow;
    boffb[f] = Cc * 64 + ((lslot ^ ((Cc >> 1) & 3)) << 4);
  }

  f32x4 acc[4][4];
#pragma unroll
  for (int mf = 0; mf < 4; ++mf)
#pragma unroll
    for (int nf = 0; nf < 4; ++nf) acc[mf][nf] = (f32x4){0.f, 0.f, 0.f, 0.f};

  auto stage = [&](int b, int t) {
    char* Ab = (char*)&Al[b][0] + wave * 1024;
    char* Bb = (char*)&Bl[b][0] + wave * 1024;
    const int ko = t * 32;
#pragma unroll
    for (int j = 0; j < 2; ++j) {
      GLOAD16(asrc[j] + ko, Ab + j * 4096);
      GLOAD16(bsrc[j] + ko, Bb + j * 4096);
    }
  };
  auto compute = [&](int b) {
    const char* Ab = (const char*)&Al[b][0];
    const char* Bb = (const char*)&Bl[b][0];
    bf16x8 af[4], bfr[4];
#pragma unroll
    for (int f = 0; f < 4; ++f) {
      af[f] = *(const bf16x8*)(Ab + aoffb[f]);
      bfr[f] = *(const bf16x8*)(Bb + boffb[f]);
    }
    __builtin_amdgcn_s_setprio(1);
#pragma unroll
    for (int mf = 0; mf < 4; ++mf)
#pragma unroll
      for (int nf = 0; nf < 4; ++nf)
        acc[mf][nf] = __builtin_amdgcn_mfma_f32_16x16x32_bf16(
            af[mf], bfr[nf], acc[mf][nf], 0, 0, 0);
    __builtin_amdgcn_s_setprio(0);
  };

  stage(0, 0);
  stage(1, 1);
  int cb = 0, pb = 2;
  for (int t = 0; t < 31; ++t) {
    VMCNT(4);
    __builtin_amdgcn_s_barrier();
    __builtin_amdgcn_sched_barrier(0);
    if (t + 2 < 32) stage(pb, t + 2);
    compute(cb);
    cb = (cb == 2) ? 0 : cb + 1;
    pb = (pb == 2) ? 0 : pb + 1;
  }
  VMCNT(0);
  __builtin_amdgcn_s_barrier();
  __builtin_amdgcn_sched_barrier(0);
  compute(cb);

  // epilogue: out[tok] += p * (acc + b2); bias only from kch==0
  const int rbase = (lane >> 4) * 4;
  const float* b2e = b2 + (size_t)e * DDIM + n0;
  float bb[4];
#pragma unroll
  for (int nf = 0; nf < 4; ++nf)
    bb[nf] = (kch == 0) ? b2e[wc + nf * 16 + lrow] : 0.f;
#pragma unroll
  for (int mf = 0; mf < 4; ++mf) {
#pragma unroll
    for (int r = 0; r < 4; ++r) {
      const int grow = wr + mf * 16 + rbase + r;
      if (m0 + grow < cnt) {
        const int assign = aoff + m0 + grow;
        const int tok = btok[assign];
        const float p = bprob[assign];
        float* orow = out + (size_t)tok * DDIM + n0;
#pragma unroll
        for (int nf = 0; nf < 4; ++nf) {
          const int cl = wc + nf * 16 + lrow;
          atomicAdd(&orow[cl], (acc[mf][nf][r] + bb[nf]) * p);
        }
      }
    }
  }
}

// ---------------- launch ----------------

extern "C" void kernel_launch(void* const* d_in, const int* in_sizes, int n_in,
                              void* d_out, int out_size, void* d_ws,
                              size_t ws_size, hipStream_t stream) {
  const float* x = (const float*)d_in[0];
  const float* Wr = (const float*)d_in[1];
  const float* br = (const float*)d_in[2];
  const float* W1 = (const float*)d_in[3];
  const float* b1 = (const float*)d_in[4];
  const float* W2 = (const float*)d_in[5];
  const float* b2 = (const float*)d_in[6];
  // d_in[7] = k (fixed 2, hardcoded)

  char* w = (char*)d_ws;
  auto alloc = [&](size_t bytes) -> char* {
    char* p = w;
    w += (bytes + 255) & ~(size_t)255;
    return p;
  };
  bf16_t* xb = (bf16_t*)alloc((size_t)NTOK * DDIM * 2);
  bf16_t* W1t = (bf16_t*)alloc((size_t)NEXP * DDIM * HDIM * 2);
  bf16_t* W2t = (bf16_t*)alloc((size_t)NEXP * DDIM * HDIM * 2);
  bf16_t* hbuf = (bf16_t*)alloc((size_t)NASSIGN * HDIM * 2);
  int* btok = (int*)alloc(NASSIGN * 4);
  float* bprob = (float*)alloc(NASSIGN * 4);
  int2* ids = (int2*)alloc(NTOK * 8);
  float2* prs = (float2*)alloc(NTOK * 8);
  int* ctrl = (int*)alloc(64);     // counts[8] + cursor[8]
  int* offsets = (int*)alloc(64);  // 9 used
  int* tmap = (int*)alloc((2 * MAX_MT + 1) * 4);
  int* counts = ctrl;
  int* cursor = ctrl + 8;
  (void)in_sizes; (void)n_in; (void)ws_size;

  float* out = (float*)d_out;

  hipMemsetAsync(d_out, 0, (size_t)out_size * 4, stream);  // atomics target
  hipMemsetAsync(ctrl, 0, 64, stream);

  transpose_cvt_kernel<<<dim3(HDIM / 32, DDIM / 64, NEXP), dim3(32, 8), 0,
                         stream>>>(W1, W1t, DDIM, HDIM);
  transpose_cvt_kernel<<<dim3(DDIM / 32, HDIM / 64, NEXP), dim3(32, 8), 0,
                         stream>>>(W2, W2t, HDIM, DDIM);
  router_kernel<<<NTOK, 256, 0, stream>>>(x, Wr, br, ids, prs, counts, xb);
  scan_aux_kernel<<<1, 256, 0, stream>>>(counts, offsets, tmap, ids, prs,
                                         out + (size_t)NTOK * DDIM);
  scatter_kernel<<<NTOK / 256, 256, 0, stream>>>(ids, prs, offsets, cursor,
                                                 btok, bprob);
  gemm1_kernel<<<GRID1, 256, 0, stream>>>(xb, W1t, b1, btok, offsets, counts,
                                          tmap, hbuf);
  gemm2_kernel<<<GRID2, 256, 0, stream>>>(hbuf, W2t, b2, btok, bprob, offsets,
                                          counts, tmap, out);
}

// Round 6
// 816.524 us; speedup vs baseline: 1.2491x; 1.1528x over previous
//
#include <hip/hip_runtime.h>
#include <hip/hip_bf16.h>

// MoE: N=8192 tokens, D=1024, H=4096, E=8 experts, top-k=2.
// Grouped GEMMs: 128x128 tile, BK=32, 3-deep circular LDS buffer,
// counted vmcnt(4) + raw s_barrier (1 barrier/K-step), XOR bank swizzle.
// gemm2: atomic-free epilogue -> per-assignment f32 partials + combine kernel.

#define NTOK 8192
#define DDIM 1024
#define HDIM 4096
#define NEXP 8
#define NASSIGN (NTOK * 2)
#define MAX_MT 135              // max ceil-sum of per-expert 128-row tiles
#define GRID1 (32 * MAX_MT)     // 4320, divisible by 8
#define GRID2A (8 * 2 * MAX_MT) // 2160, divisible by 8 (K-split x2, no atomics)
#define GRID2B (8 * MAX_MT)     // 1080, divisible by 8 (atomic fallback)

typedef __bf16 bf16_t;
typedef __bf16 bf16x2 __attribute__((ext_vector_type(2)));
typedef __bf16 bf16x4 __attribute__((ext_vector_type(4)));
typedef __bf16 bf16x8 __attribute__((ext_vector_type(8)));
typedef float f32x4 __attribute__((ext_vector_type(4)));

#define GLOAD16(gptr, lptr)                                                    \
  __builtin_amdgcn_global_load_lds(                                            \
      (const __attribute__((address_space(1))) void*)(gptr),                   \
      (__attribute__((address_space(3))) void*)(lptr), 16, 0, 0)

#define VMCNT(n) asm volatile("s_waitcnt vmcnt(" #n ")" ::: "memory")

// bijective XCD swizzle: launched id -> logical job; nwg % 8 == 0
__device__ __forceinline__ int xcd_swz(int orig, int nwg) {
  const int cpx = nwg >> 3;
  return (orig & 7) * cpx + (orig >> 3);
}

// ---------------- weight transpose: [E][R][C] f32 -> [E][C][R] bf16 --------
__global__ void __launch_bounds__(256) transpose_cvt_kernel(
    const float* __restrict__ in, bf16_t* __restrict__ out, int R, int C) {
  __shared__ float tile[64][33];
  const size_t mat = (size_t)R * C;
  const float* ip = in + (size_t)blockIdx.z * mat;
  bf16_t* op = out + (size_t)blockIdx.z * mat;
  const int c0 = blockIdx.x * 32, r0 = blockIdx.y * 64;
  const int tx = threadIdx.x, ty = threadIdx.y;  // (32, 8)
#pragma unroll
  for (int i = 0; i < 8; ++i) {
    const int r = ty + 8 * i;
    tile[r][tx] = ip[(size_t)(r0 + r) * C + (c0 + tx)];
  }
  __syncthreads();
#pragma unroll
  for (int j = 0; j < 4; ++j) {
    const int c = ty + 8 * j;
    bf16x2 v;
    v[0] = (bf16_t)tile[2 * tx][c];
    v[1] = (bf16_t)tile[2 * tx + 1][c];
    *(bf16x2*)(op + (size_t)(c0 + c) * R + r0 + 2 * tx) = v;
  }
}

// ---------------- router (fused x -> bf16; wave-shuffle reduce) ------------
__global__ void __launch_bounds__(256) router_kernel(
    const float* __restrict__ x, const float* __restrict__ Wr,
    const float* __restrict__ br, int2* __restrict__ ids,
    float2* __restrict__ prs, int* __restrict__ counts,
    bf16_t* __restrict__ xb) {
  const int n = blockIdx.x;
  const int t = threadIdx.x;
  const int wave = t >> 6, lane = t & 63;
  const float4 xv = ((const float4*)(x + (size_t)n * DDIM))[t];
  bf16x4 o;
  o[0] = (bf16_t)xv.x; o[1] = (bf16_t)xv.y;
  o[2] = (bf16_t)xv.z; o[3] = (bf16_t)xv.w;
  ((bf16x4*)(xb + (size_t)n * DDIM))[t] = o;

  float acc[NEXP];
#pragma unroll
  for (int e = 0; e < NEXP; ++e) acc[e] = 0.f;
  const float xq[4] = {xv.x, xv.y, xv.z, xv.w};
#pragma unroll
  for (int q = 0; q < 4; ++q) {
    const float* w = Wr + (size_t)(4 * t + q) * NEXP;
#pragma unroll
    for (int e = 0; e < NEXP; ++e) acc[e] += xq[q] * w[e];
  }
#pragma unroll
  for (int off = 32; off >= 1; off >>= 1)
#pragma unroll
    for (int e = 0; e < NEXP; ++e) acc[e] += __shfl_down(acc[e], off);
  __shared__ float red[4][NEXP];
  if (lane == 0)
#pragma unroll
    for (int e = 0; e < NEXP; ++e) red[wave][e] = acc[e];
  __syncthreads();
  if (t == 0) {
    float l[NEXP];
#pragma unroll
    for (int e = 0; e < NEXP; ++e)
      l[e] = ((red[0][e] + red[1][e]) + (red[2][e] + red[3][e])) + br[e];
    int i1 = 0; float v1 = l[0];
    for (int e = 1; e < NEXP; ++e)
      if (l[e] > v1) { v1 = l[e]; i1 = e; }
    int i2 = (i1 == 0) ? 1 : 0; float v2 = l[i2];
    for (int e = 0; e < NEXP; ++e)
      if (e != i1 && l[e] > v2) { v2 = l[e]; i2 = e; }
    float denom = 0.f;
    for (int e = 0; e < NEXP; ++e) denom += expf(l[e] - v1);
    ids[n] = make_int2(i1, i2);
    prs[n] = make_float2(1.f / denom, expf(v2 - v1) / denom);
    atomicAdd(&counts[i1], 1);
    atomicAdd(&counts[i2], 1);
  }
}

// scan (thread 0) + aux loss
__global__ void __launch_bounds__(256) scan_aux_kernel(
    const int* __restrict__ counts, int* __restrict__ offsets,
    int* __restrict__ tmap, const int2* __restrict__ ids,
    const float2* __restrict__ prs, float* __restrict__ aux_out) {
  const int t = threadIdx.x;
  if (t == 0) {
    int off = 0, nt = 0;
    for (int e = 0; e < NEXP; ++e) {
      offsets[e] = off;
      const int c = counts[e];
      for (int m0 = 0; m0 < c; m0 += 128) {
        tmap[nt] = e;
        tmap[MAX_MT + nt] = m0;
        ++nt;
      }
      off += c;
    }
    offsets[NEXP] = off;
    tmap[2 * MAX_MT] = nt;
  }
  float imp[NEXP];
#pragma unroll
  for (int e = 0; e < NEXP; ++e) imp[e] = 0.f;
  for (int n = t; n < NTOK; n += 256) {
    const int2 id = ids[n];
    const float2 pr = prs[n];
#pragma unroll
    for (int e = 0; e < NEXP; ++e)
      imp[e] += (id.x == e ? pr.x : 0.f) + (id.y == e ? pr.y : 0.f);
  }
  __shared__ float red[256][NEXP];
#pragma unroll
  for (int e = 0; e < NEXP; ++e) red[t][e] = imp[e];
  __syncthreads();
  for (int s = 128; s >= 1; s >>= 1) {
    if (t < s) {
#pragma unroll
      for (int e = 0; e < NEXP; ++e) red[t][e] += red[t + s][e];
    }
    __syncthreads();
  }
  if (t == 0) {
    float m = 0.f;
    for (int e = 0; e < NEXP; ++e) m += red[0][e];
    m *= (1.f / NEXP);
    float v = 0.f;
    for (int e = 0; e < NEXP; ++e) {
      const float d = red[0][e] - m;
      v += d * d;
    }
    v *= (1.f / (NEXP - 1));  // ddof=1
    aux_out[0] = v / (m * m + 1e-9f);
  }
}

// scatter: bucket tokens; also record token -> (assign1, assign2)
__global__ void __launch_bounds__(256) scatter_kernel(
    const int2* __restrict__ ids, const float2* __restrict__ prs,
    const int* __restrict__ offsets, int* __restrict__ cursor,
    int* __restrict__ btok, float* __restrict__ bprob,
    int2* __restrict__ amap) {
  const int n = blockIdx.x * 256 + threadIdx.x;
  if (n >= NTOK) return;
  const int2 id = ids[n];
  const float2 pr = prs[n];
  int p = atomicAdd(&cursor[id.x], 1);
  const int a1 = offsets[id.x] + p;
  btok[a1] = n;
  bprob[a1] = pr.x;
  p = atomicAdd(&cursor[id.y], 1);
  const int a2 = offsets[id.y] + p;
  btok[a2] = n;
  bprob[a2] = pr.y;
  amap[n] = make_int2(a1, a2);
}

// combine: out[n] = p1*(o0+o1)[a1] + p2*(o0+o1)[a2]  (bias already in o0)
__global__ void __launch_bounds__(256) combine_kernel(
    const float* __restrict__ o0, const float* __restrict__ o1,
    const int2* __restrict__ amap, const float* __restrict__ bprob,
    float* __restrict__ out) {
  const int n = blockIdx.x;
  const int d = threadIdx.x * 4;
  const int2 a = amap[n];
  const float p1 = bprob[a.x], p2 = bprob[a.y];
  const float4 u0 = *(const float4*)(o0 + (size_t)a.x * DDIM + d);
  const float4 u1 = *(const float4*)(o1 + (size_t)a.x * DDIM + d);
  const float4 v0 = *(const float4*)(o0 + (size_t)a.y * DDIM + d);
  const float4 v1 = *(const float4*)(o1 + (size_t)a.y * DDIM + d);
  float4 r;
  r.x = p1 * (u0.x + u1.x) + p2 * (v0.x + v1.x);
  r.y = p1 * (u0.y + u1.y) + p2 * (v0.y + v1.y);
  r.z = p1 * (u0.z + u1.z) + p2 * (v0.z + v1.z);
  r.w = p1 * (u0.w + u1.w) + p2 * (v0.w + v1.w);
  *(float4*)(out + (size_t)n * DDIM + d) = r;
}

// ---------------- grouped GEMMs: 128x128, BK=32, 3-buffer counted pipeline --
// Per K-step: vmcnt(4) -> s_barrier -> sched_barrier(ALU-pass) ->
// stage tile t+2 -> 8 ds_read_b128 (XOR-swizzled) -> 16 MFMA.

// h[assign, :] = relu(x[btok[assign]] @ W1[e] + b1[e]);  N = HDIM, K = DDIM
__global__ void __launch_bounds__(256, 3) gemm1_kernel(
    const bf16_t* __restrict__ xb, const bf16_t* __restrict__ W1t,
    const float* __restrict__ b1, const int* __restrict__ btok,
    const int* __restrict__ offsets, const int* __restrict__ counts,
    const int* __restrict__ tmap, bf16_t* __restrict__ h) {
  const int job = xcd_swz((int)blockIdx.x, GRID1);
  const int tidx = job >> 5;
  const int nblk = job & 31;
  if (tidx >= tmap[2 * MAX_MT]) return;
  const int e = tmap[tidx];
  const int m0 = tmap[MAX_MT + tidx];
  const int cnt = counts[e];
  const int aoff = offsets[e];
  const int n0 = nblk * 128;

  __shared__ __align__(16) bf16_t Al[3][128 * 32];
  __shared__ __align__(16) bf16_t Bl[3][128 * 32];

  const int tid = threadIdx.x;
  const int wave = tid >> 6;
  const int lane = tid & 63;

  const bf16_t* asrc[2];
  const bf16_t* bsrc[2];
#pragma unroll
  for (int j = 0; j < 2; ++j) {
    const int c = j * 256 + tid;
    const int r = c >> 2;
    const int slot = (c & 3) ^ ((r >> 1) & 3);
    int arow = m0 + r;
    if (arow > cnt - 1) arow = cnt - 1;
    asrc[j] = xb + (size_t)btok[aoff + arow] * DDIM + slot * 8;
    bsrc[j] = W1t + ((size_t)e * HDIM + n0 + r) * DDIM + slot * 8;
  }

  const int wr = (wave >> 1) * 64;
  const int wc = (wave & 1) * 64;
  const int lrow = lane & 15;
  const int lslot = lane >> 4;

  int aoffb[4], boffb[4];
#pragma unroll
  for (int f = 0; f < 4; ++f) {
    const int Rr = wr + f * 16 + lrow;
    aoffb[f] = Rr * 64 + ((lslot ^ ((Rr >> 1) & 3)) << 4);
    const int Cc = wc + f * 16 + lrow;
    boffb[f] = Cc * 64 + ((lslot ^ ((Cc >> 1) & 3)) << 4);
  }

  f32x4 acc[4][4];
#pragma unroll
  for (int mf = 0; mf < 4; ++mf)
#pragma unroll
    for (int nf = 0; nf < 4; ++nf) acc[mf][nf] = (f32x4){0.f, 0.f, 0.f, 0.f};

  auto stage = [&](int b, int t) {
    char* Ab = (char*)&Al[b][0] + wave * 1024;
    char* Bb = (char*)&Bl[b][0] + wave * 1024;
    const int ko = t * 32;
#pragma unroll
    for (int j = 0; j < 2; ++j) {
      GLOAD16(asrc[j] + ko, Ab + j * 4096);
      GLOAD16(bsrc[j] + ko, Bb + j * 4096);
    }
  };
  auto compute = [&](int b) {
    const char* Ab = (const char*)&Al[b][0];
    const char* Bb = (const char*)&Bl[b][0];
    bf16x8 af[4], bfr[4];
#pragma unroll
    for (int f = 0; f < 4; ++f) {
      af[f] = *(const bf16x8*)(Ab + aoffb[f]);
      bfr[f] = *(const bf16x8*)(Bb + boffb[f]);
    }
    __builtin_amdgcn_s_setprio(1);
#pragma unroll
    for (int mf = 0; mf < 4; ++mf)
#pragma unroll
      for (int nf = 0; nf < 4; ++nf)
        acc[mf][nf] = __builtin_amdgcn_mfma_f32_16x16x32_bf16(
            af[mf], bfr[nf], acc[mf][nf], 0, 0, 0);
    __builtin_amdgcn_s_setprio(0);
  };

  stage(0, 0);
  stage(1, 1);
  int cb = 0, pb = 2;
  for (int t = 0; t < 31; ++t) {
    VMCNT(4);
    __builtin_amdgcn_s_barrier();
    __builtin_amdgcn_sched_barrier(0x1);
    if (t + 2 < 32) stage(pb, t + 2);
    compute(cb);
    cb = (cb == 2) ? 0 : cb + 1;
    pb = (pb == 2) ? 0 : pb + 1;
  }
  VMCNT(0);
  __builtin_amdgcn_s_barrier();
  __builtin_amdgcn_sched_barrier(0x1);
  compute(cb);

  const int rbase = (lane >> 4) * 4;
  const float* b1e = b1 + (size_t)e * HDIM + n0;
#pragma unroll
  for (int nf = 0; nf < 4; ++nf) {
    const int cl = wc + nf * 16 + lrow;
    const float bb = b1e[cl];
#pragma unroll
    for (int mf = 0; mf < 4; ++mf) {
#pragma unroll
      for (int r = 0; r < 4; ++r) {
        const int grow = wr + mf * 16 + rbase + r;
        if (m0 + grow < cnt)
          h[(size_t)(aoff + m0 + grow) * HDIM + (n0 + cl)] =
              (bf16_t)fmaxf(acc[mf][nf][r] + bb, 0.f);
      }
    }
  }
}

// gemm2: per-assignment partials (no atomics) or atomic fallback.
// NT = K-steps per block; KSP = K-split factor.
template <int NT, int KSP, bool ATOMIC>
__global__ void __launch_bounds__(256, 3) gemm2_kernel(
    const bf16_t* __restrict__ h, const bf16_t* __restrict__ W2t,
    const float* __restrict__ b2, const int* __restrict__ btok,
    const float* __restrict__ bprob, const int* __restrict__ offsets,
    const int* __restrict__ counts, const int* __restrict__ tmap,
    float* __restrict__ o0, float* __restrict__ o1,
    float* __restrict__ out) {
  const int nwg = 8 * KSP * MAX_MT;
  const int job = xcd_swz((int)blockIdx.x, nwg);
  const int tidx = job / (8 * KSP);
  const int rem = job % (8 * KSP);
  const int nblk = rem & 7;
  const int kch = rem >> 3;
  if (tidx >= tmap[2 * MAX_MT]) return;
  const int e = tmap[tidx];
  const int m0 = tmap[MAX_MT + tidx];
  const int cnt = counts[e];
  const int aoff = offsets[e];
  const int n0 = nblk * 128;
  const int kbase = kch * (HDIM / KSP);

  __shared__ __align__(16) bf16_t Al[3][128 * 32];
  __shared__ __align__(16) bf16_t Bl[3][128 * 32];

  const int tid = threadIdx.x;
  const int wave = tid >> 6;
  const int lane = tid & 63;

  const bf16_t* asrc[2];
  const bf16_t* bsrc[2];
#pragma unroll
  for (int j = 0; j < 2; ++j) {
    const int c = j * 256 + tid;
    const int r = c >> 2;
    const int slot = (c & 3) ^ ((r >> 1) & 3);
    int arow = m0 + r;
    if (arow > cnt - 1) arow = cnt - 1;
    asrc[j] = h + (size_t)(aoff + arow) * HDIM + kbase + slot * 8;
    bsrc[j] = W2t + ((size_t)e * DDIM + n0 + r) * HDIM + kbase + slot * 8;
  }

  const int wr = (wave >> 1) * 64;
  const int wc = (wave & 1) * 64;
  const int lrow = lane & 15;
  const int lslot = lane >> 4;

  int aoffb[4], boffb[4];
#pragma unroll
  for (int f = 0; f < 4; ++f) {
    const int Rr = wr + f * 16 + lrow;
    aoffb[f] = Rr * 64 + ((lslot ^ ((Rr >> 1) & 3)) << 4);
    const int Cc = wc + f * 16 + lrow;
    boffb[f] = Cc * 64 + ((lslot ^ ((Cc >> 1) & 3)) << 4);
  }

  f32x4 acc[4][4];
#pragma unroll
  for (int mf = 0; mf < 4; ++mf)
#pragma unroll
    for (int nf = 0; nf < 4; ++nf) acc[mf][nf] = (f32x4){0.f, 0.f, 0.f, 0.f};

  auto stage = [&](int b, int t) {
    char* Ab = (char*)&Al[b][0] + wave * 1024;
    char* Bb = (char*)&Bl[b][0] + wave * 1024;
    const int ko = t * 32;
#pragma unroll
    for (int j = 0; j < 2; ++j) {
      GLOAD16(asrc[j] + ko, Ab + j * 4096);
      GLOAD16(bsrc[j] + ko, Bb + j * 4096);
    }
  };
  auto compute = [&](int b) {
    const char* Ab = (const char*)&Al[b][0];
    const char* Bb = (const char*)&Bl[b][0];
    bf16x8 af[4], bfr[4];
#pragma unroll
    for (int f = 0; f < 4; ++f) {
      af[f] = *(const bf16x8*)(Ab + aoffb[f]);
      bfr[f] = *(const bf16x8*)(Bb + boffb[f]);
    }
    __builtin_amdgcn_s_setprio(1);
#pragma unroll
    for (int mf = 0; mf < 4; ++mf)
#pragma unroll
      for (int nf = 0; nf < 4; ++nf)
        acc[mf][nf] = __builtin_amdgcn_mfma_f32_16x16x32_bf16(
            af[mf], bfr[nf], acc[mf][nf], 0, 0, 0);
    __builtin_amdgcn_s_setprio(0);
  };

  stage(0, 0);
  stage(1, 1);
  int cb = 0, pb = 2;
  for (int t = 0; t < NT - 1; ++t) {
    VMCNT(4);
    __builtin_amdgcn_s_barrier();
    __builtin_amdgcn_sched_barrier(0x1);
    if (t + 2 < NT) stage(pb, t + 2);
    compute(cb);
    cb = (cb == 2) ? 0 : cb + 1;
    pb = (pb == 2) ? 0 : pb + 1;
  }
  VMCNT(0);
  __builtin_amdgcn_s_barrier();
  __builtin_amdgcn_sched_barrier(0x1);
  compute(cb);

  const int rbase = (lane >> 4) * 4;
  const float* b2e = b2 + (size_t)e * DDIM + n0;
  float bb[4];
#pragma unroll
  for (int nf = 0; nf < 4; ++nf)
    bb[nf] = (kch == 0) ? b2e[wc + nf * 16 + lrow] : 0.f;

  if (ATOMIC) {
#pragma unroll
    for (int mf = 0; mf < 4; ++mf) {
#pragma unroll
      for (int r = 0; r < 4; ++r) {
        const int grow = wr + mf * 16 + rbase + r;
        if (m0 + grow < cnt) {
          const int assign = aoff + m0 + grow;
          const int tok = btok[assign];
          const float p = bprob[assign];
          float* orow = out + (size_t)tok * DDIM + n0;
#pragma unroll
          for (int nf = 0; nf < 4; ++nf) {
            const int cl = wc + nf * 16 + lrow;
            atomicAdd(&orow[cl], (acc[mf][nf][r] + bb[nf]) * p);
          }
        }
      }
    }
  } else {
    float* obase = (kch == 0) ? o0 : o1;
#pragma unroll
    for (int mf = 0; mf < 4; ++mf) {
#pragma unroll
      for (int r = 0; r < 4; ++r) {
        const int grow = wr + mf * 16 + rbase + r;
        if (m0 + grow < cnt) {
          const int assign = aoff + m0 + grow;
          float* orow = obase + (size_t)assign * DDIM + n0;
#pragma unroll
          for (int nf = 0; nf < 4; ++nf) {
            const int cl = wc + nf * 16 + lrow;
            orow[cl] = acc[mf][nf][r] + bb[nf];
          }
        }
      }
    }
  }
}

// ---------------- launch ----------------

extern "C" void kernel_launch(void* const* d_in, const int* in_sizes, int n_in,
                              void* d_out, int out_size, void* d_ws,
                              size_t ws_size, hipStream_t stream) {
  const float* x = (const float*)d_in[0];
  const float* Wr = (const float*)d_in[1];
  const float* br = (const float*)d_in[2];
  const float* W1 = (const float*)d_in[3];
  const float* b1 = (const float*)d_in[4];
  const float* W2 = (const float*)d_in[5];
  const float* b2 = (const float*)d_in[6];
  // d_in[7] = k (fixed 2, hardcoded)

  char* w = (char*)d_ws;
  auto alloc = [&](size_t bytes) -> char* {
    char* p = w;
    w += (bytes + 255) & ~(size_t)255;
    return p;
  };
  bf16_t* xb = (bf16_t*)alloc((size_t)NTOK * DDIM * 2);            // 16.8 MB
  bf16_t* W1t = (bf16_t*)alloc((size_t)NEXP * DDIM * HDIM * 2);    // 67.1 MB
  bf16_t* W2t = (bf16_t*)alloc((size_t)NEXP * DDIM * HDIM * 2);    // 67.1 MB
  bf16_t* hbuf = (bf16_t*)alloc((size_t)NASSIGN * HDIM * 2);       // 134 MB
  int* btok = (int*)alloc(NASSIGN * 4);
  float* bprob = (float*)alloc(NASSIGN * 4);
  int2* ids = (int2*)alloc(NTOK * 8);
  float2* prs = (float2*)alloc(NTOK * 8);
  int2* amap = (int2*)alloc(NTOK * 8);
  int* ctrl = (int*)alloc(64);     // counts[8] + cursor[8]
  int* offsets = (int*)alloc(64);  // 9 used
  int* tmap = (int*)alloc((2 * MAX_MT + 1) * 4);
  int* counts = ctrl;
  int* cursor = ctrl + 8;
  // o0: fresh region after everything; o1: overlays dead xb+W1t (67.1<83.9MB)
  const size_t osz = (size_t)NASSIGN * DDIM * 4;  // 67.1 MB
  float* o0 = (float*)alloc(osz);
  float* o1 = (float*)d_ws;  // valid only during/after gemm2 (xb,W1t dead)
  const size_t needed = (size_t)(w - (char*)d_ws);
  const bool pathA = ws_size >= needed;
  (void)in_sizes; (void)n_in;

  float* out = (float*)d_out;

  hipMemsetAsync(ctrl, 0, 64, stream);
  if (!pathA)
    hipMemsetAsync(d_out, 0, (size_t)out_size * 4, stream);  // atomics target

  transpose_cvt_kernel<<<dim3(HDIM / 32, DDIM / 64, NEXP), dim3(32, 8), 0,
                         stream>>>(W1, W1t, DDIM, HDIM);
  transpose_cvt_kernel<<<dim3(DDIM / 32, HDIM / 64, NEXP), dim3(32, 8), 0,
                         stream>>>(W2, W2t, HDIM, DDIM);
  router_kernel<<<NTOK, 256, 0, stream>>>(x, Wr, br, ids, prs, counts, xb);
  scan_aux_kernel<<<1, 256, 0, stream>>>(counts, offsets, tmap, ids, prs,
                                         out + (size_t)NTOK * DDIM);
  scatter_kernel<<<NTOK / 256, 256, 0, stream>>>(ids, prs, offsets, cursor,
                                                 btok, bprob, amap);
  gemm1_kernel<<<GRID1, 256, 0, stream>>>(xb, W1t, b1, btok, offsets, counts,
                                          tmap, hbuf);
  if (pathA) {
    gemm2_kernel<64, 2, false><<<GRID2A, 256, 0, stream>>>(
        hbuf, W2t, b2, btok, bprob, offsets, counts, tmap, o0, o1, out);
    combine_kernel<<<NTOK, 256, 0, stream>>>(o0, o1, amap, bprob, out);
  } else {
    gemm2_kernel<128, 1, true><<<GRID2B, 256, 0, stream>>>(
        hbuf, W2t, b2, btok, bprob, offsets, counts, tmap, o0, o1, out);
  }
}